// Round 1
// baseline (602.372 us; speedup 1.0000x reference)
//
#include <hip/hip_runtime.h>

#define CIN  128
#define COUT 64
#define KVOL 4
#define TM   32
#define FLS  132   // feat LDS row stride (words): 4*FLS % 32 == 16 -> conflict-free/2-way reads
#define BN_EPS 1e-5f

// ws layout (bytes):
//   0    int counts[4]
//   16   int cursors[4]
//   32   int bin_base[5]
//   64   int tile_base[5]
//   128  float gsum[64]
//   384  float gsq[64]
//   1024 int order[M]

__device__ inline float4 fma4(float4 a, float s, float4 b) {
  a.x = fmaf(s, b.x, a.x); a.y = fmaf(s, b.y, a.y);
  a.z = fmaf(s, b.z, a.z); a.w = fmaf(s, b.w, a.w);
  return a;
}

__global__ void k_hist(const int* __restrict__ kidx, int M, int* __restrict__ ws_i) {
  __shared__ int h[KVOL];
  int t = threadIdx.x;
  if (t < KVOL) h[t] = 0;
  __syncthreads();
  int c0 = 0, c1 = 0, c2 = 0, c3 = 0;
  for (int m = blockIdx.x * blockDim.x + t; m < M; m += gridDim.x * blockDim.x) {
    int k = kidx[m] & 3;
    c0 += (k == 0); c1 += (k == 1); c2 += (k == 2); c3 += (k == 3);
  }
  atomicAdd(&h[0], c0); atomicAdd(&h[1], c1);
  atomicAdd(&h[2], c2); atomicAdd(&h[3], c3);
  __syncthreads();
  if (t < KVOL) atomicAdd(&ws_i[t], h[t]);
}

__global__ void k_prefix(int* __restrict__ ws_i) {
  int* counts    = ws_i;
  int* bin_base  = ws_i + 8;
  int* tile_base = ws_i + 16;
  int b = 0, tb = 0;
  for (int k = 0; k < KVOL; ++k) {
    bin_base[k]  = b;
    tile_base[k] = tb;
    b  += counts[k];
    tb += (counts[k] + TM - 1) / TM;
  }
  bin_base[KVOL]  = b;
  tile_base[KVOL] = tb;
}

__global__ void k_scatter(const int* __restrict__ kidx, int M,
                          int* __restrict__ ws_i, int* __restrict__ order) {
  __shared__ int lcount[KVOL];
  __shared__ int lbase[KVOL];
  int t = threadIdx.x;
  int* cursors = ws_i + 4;
  const int* bin_base = ws_i + 8;
  for (int base = blockIdx.x * blockDim.x; base < M; base += gridDim.x * blockDim.x) {
    int m = base + t;
    int k = 0, rank = 0;
    if (t < KVOL) lcount[t] = 0;
    __syncthreads();
    if (m < M) { k = kidx[m] & 3; rank = atomicAdd(&lcount[k], 1); }
    __syncthreads();
    if (t < KVOL) lbase[t] = atomicAdd(&cursors[t], lcount[t]);
    __syncthreads();
    if (m < M) order[bin_base[k] + lbase[k] + rank] = m;
    __syncthreads();
  }
}

__global__ __launch_bounds__(256, 2)
void k_gemm(const float* __restrict__ feats, const float* __restrict__ weight,
            const int* __restrict__ in_idx, const int* __restrict__ order,
            const int* __restrict__ ws_i, float* __restrict__ out,
            float* __restrict__ gsum, float* __restrict__ gsq) {
  __shared__ float Wl[CIN][COUT];   // 32 KB
  __shared__ float Fl[TM][FLS];     // 16.9 KB
  const int* counts    = ws_i;
  const int* bin_base  = ws_i + 8;
  const int* tile_base = ws_i + 16;

  int b = blockIdx.x;
  if (b >= tile_base[KVOL]) return;          // uniform exit, before any barrier
  int k = 0;
  while (b >= tile_base[k + 1]) ++k;         // k in [0,4)
  int tile = b - tile_base[k];
  int cnt  = counts[k];
  int row0 = tile * TM;
  int base = bin_base[k];
  int t = threadIdx.x;

  // stage W[k] (linear copy, 8 float4 per thread)
  {
    const float4* src = (const float4*)(weight + k * CIN * COUT);
    float4* dst = (float4*)&Wl[0][0];
    #pragma unroll
    for (int j = t; j < CIN * COUT / 4; j += 256) dst[j] = src[j];
  }
  // stage gathered feat tile: 8 threads per row, 4 float4 each
  {
    int r = t >> 3, l8 = t & 7;
    int gr = row0 + r;
    float4 v[4];
    if (gr < cnt) {
      int m = order[base + gr];
      long g = in_idx[m];
      const float4* src = (const float4*)(feats + g * CIN) + l8 * 4;
      v[0] = src[0]; v[1] = src[1]; v[2] = src[2]; v[3] = src[3];
    } else {
      v[0] = v[1] = v[2] = v[3] = make_float4(0.f, 0.f, 0.f, 0.f);
    }
    #pragma unroll
    for (int jj = 0; jj < 4; ++jj)
      *(float4*)&Fl[r][l8 * 16 + jj * 4] = v[jj];
  }
  __syncthreads();

  int tx = t & 15, ty = t >> 4;   // cols 4tx..4tx+3, rows 2ty..2ty+1
  float4 acc0 = make_float4(0.f, 0.f, 0.f, 0.f);
  float4 acc1 = make_float4(0.f, 0.f, 0.f, 0.f);

  #pragma unroll 4
  for (int i = 0; i < CIN; i += 4) {
    float4 a0 = *(const float4*)&Fl[2 * ty][i];
    float4 a1 = *(const float4*)&Fl[2 * ty + 1][i];
    float4 b0 = *(const float4*)&Wl[i][4 * tx];
    float4 b1 = *(const float4*)&Wl[i + 1][4 * tx];
    float4 b2 = *(const float4*)&Wl[i + 2][4 * tx];
    float4 b3 = *(const float4*)&Wl[i + 3][4 * tx];
    acc0 = fma4(acc0, a0.x, b0); acc0 = fma4(acc0, a0.y, b1);
    acc0 = fma4(acc0, a0.z, b2); acc0 = fma4(acc0, a0.w, b3);
    acc1 = fma4(acc1, a1.x, b0); acc1 = fma4(acc1, a1.y, b1);
    acc1 = fma4(acc1, a1.z, b2); acc1 = fma4(acc1, a1.w, b3);
  }

  // store rows + per-thread column partials (valid rows only)
  float s0 = 0.f, s1 = 0.f, s2 = 0.f, s3 = 0.f;
  float q0 = 0.f, q1 = 0.f, q2 = 0.f, q3 = 0.f;
  #pragma unroll
  for (int rr = 0; rr < 2; ++rr) {
    int gr = row0 + 2 * ty + rr;
    float4 a = rr ? acc1 : acc0;
    if (gr < cnt) {
      int m = order[base + gr];
      *(float4*)&out[(long)m * COUT + 4 * tx] = a;
      s0 += a.x; s1 += a.y; s2 += a.z; s3 += a.w;
      q0 += a.x * a.x; q1 += a.y * a.y; q2 += a.z * a.z; q3 += a.w * a.w;
    }
  }

  __syncthreads();                         // done reading Fl; reuse as scratch
  float* redS = &Fl[0][0];                 // [16][64]
  float* redQ = redS + 1024;               // [16][64]
  *(float4*)&redS[ty * 64 + 4 * tx] = make_float4(s0, s1, s2, s3);
  *(float4*)&redQ[ty * 64 + 4 * tx] = make_float4(q0, q1, q2, q3);
  __syncthreads();
  if (t < COUT) {
    float fs = 0.f, fq = 0.f;
    #pragma unroll
    for (int g = 0; g < 16; ++g) { fs += redS[g * 64 + t]; fq += redQ[g * 64 + t]; }
    atomicAdd(&gsum[t], fs);
    atomicAdd(&gsq[t], fq);
  }
}

__global__ void k_norm(float* __restrict__ out,
                       const float* __restrict__ gsum, const float* __restrict__ gsq,
                       const float* __restrict__ gamma, const float* __restrict__ beta,
                       int M) {
  long total = (long)M * COUT / 4;
  long T0 = (long)blockIdx.x * blockDim.x + threadIdx.x;
  int c0 = (int)((T0 * 4) & 63);
  float4 sm = *(const float4*)&gsum[c0];
  float4 sq = *(const float4*)&gsq[c0];
  float inv = 1.0f / (float)M;
  float mx = sm.x * inv, my = sm.y * inv, mz = sm.z * inv, mw = sm.w * inv;
  float rx = rsqrtf(sq.x * inv - mx * mx + BN_EPS);
  float ry = rsqrtf(sq.y * inv - my * my + BN_EPS);
  float rz = rsqrtf(sq.z * inv - mz * mz + BN_EPS);
  float rw = rsqrtf(sq.w * inv - mw * mw + BN_EPS);
  float4 ga = *(const float4*)&gamma[c0];
  float4 be = *(const float4*)&beta[c0];
  float scx = rx * ga.x, scy = ry * ga.y, scz = rz * ga.z, scw = rw * ga.w;
  float shx = be.x - mx * scx, shy = be.y - my * scy;
  float shz = be.z - mz * scz, shw = be.w - mw * scw;
  float4* o4 = (float4*)out;
  long stride = (long)gridDim.x * blockDim.x;
  for (long j = T0; j < total; j += stride) {
    float4 v = o4[j];
    v.x = fmaxf(fmaf(v.x, scx, shx), 0.f);
    v.y = fmaxf(fmaf(v.y, scy, shy), 0.f);
    v.z = fmaxf(fmaf(v.z, scz, shz), 0.f);
    v.w = fmaxf(fmaf(v.w, scw, shw), 0.f);
    o4[j] = v;
  }
}

extern "C" void kernel_launch(void* const* d_in, const int* in_sizes, int n_in,
                              void* d_out, int out_size, void* d_ws, size_t ws_size,
                              hipStream_t stream) {
  const float* feats  = (const float*)d_in[0];
  const float* weight = (const float*)d_in[1];
  const float* gamma  = (const float*)d_in[2];
  const float* beta   = (const float*)d_in[3];
  const int*   in_idx = (const int*)d_in[4];
  const int*   kidx   = (const int*)d_in[5];
  int M = in_sizes[4];
  float* out = (float*)d_out;

  int*   ws_i  = (int*)d_ws;
  float* gsum  = (float*)((char*)d_ws + 128);
  float* gsq   = (float*)((char*)d_ws + 384);
  int*   order = (int*)((char*)d_ws + 1024);

  hipMemsetAsync(d_ws, 0, 1024, stream);
  k_hist<<<1024, 256, 0, stream>>>(kidx, M, ws_i);
  k_prefix<<<1, 1, 0, stream>>>(ws_i);
  k_scatter<<<1024, 256, 0, stream>>>(kidx, M, ws_i, order);

  int nTiles = (M + TM - 1) / TM + KVOL;   // upper bound; extras exit early
  k_gemm<<<nTiles, 256, 0, stream>>>(feats, weight, in_idx, order, ws_i, out, gsum, gsq);

  k_norm<<<2048, 256, 0, stream>>>(out, gsum, gsq, gamma, beta, M);
}

// Round 2
// 214.583 us; speedup vs baseline: 2.8072x; 2.8072x over previous
//
#include <hip/hip_runtime.h>

#define CIN  128
#define COUT 64
#define KVOL 4
#define TMR  128          // rows per block
#define BN_EPS 1e-5f

typedef __bf16 bf16x8 __attribute__((ext_vector_type(8)));
typedef float  f32x4  __attribute__((ext_vector_type(4)));
typedef float  f32x8  __attribute__((ext_vector_type(8)));

// ws layout (bytes):
//   128  float gsum[64]
//   384  float gsq[64]
//   1024 __bf16 wfrag[4][4][4][64][8]   (64 KB, fragment-ordered weights)

// Pre-arrange W into MFMA B-fragment order, converted to bf16.
// wfrag[k][f][ks][lane][j] = W[k][ ks*32 + (lane>>4)*8 + j ][ f*16 + (lane&15) ]
// (A and B use the same lane->k formula, so any consistent k permutation is valid.)
__global__ void k_prepw(const float* __restrict__ weight, __bf16* __restrict__ wfrag) {
  int id = blockIdx.x * 256 + threadIdx.x;       // 0..32767
  int j  = id & 7;
  int l  = (id >> 3) & 63;
  int ks = (id >> 9) & 3;
  int f  = (id >> 11) & 3;
  int k  = id >> 13;
  int kk = ks * 32 + (l >> 4) * 8 + j;
  int n  = f * 16 + (l & 15);
  wfrag[id] = (__bf16)weight[(k * CIN + kk) * COUT + n];
}

__device__ inline bf16x8 sel8(bool c, bf16x8 a, bf16x8 z) { return c ? a : z; }

__global__ __launch_bounds__(256, 2)
void k_gemm(const float* __restrict__ feats, const int* __restrict__ in_idx,
            const int* __restrict__ kidx, const __bf16* __restrict__ wfrag,
            float* __restrict__ out, float* __restrict__ gsum, float* __restrict__ gsq,
            int M) {
  __shared__ char Fl[TMR * 256];   // 32 KB: 128 rows x 128 bf16, XOR-swizzled
  __shared__ int  ki[TMR];

  int m0 = blockIdx.x * TMR;
  int t  = threadIdx.x;

  // ---- stage: gather feat rows, cvt f32->bf16, swizzled LDS write ----
  {
    int r = t >> 1, h = t & 1;
    int m = m0 + r;
    bool v = (m < M);
    if (h == 0) ki[r] = v ? kidx[m] : -1;
    int g = v ? in_idx[m] : 0;
    const float* src = feats + (long)g * CIN + h * 64;
    char* dst = Fl + r * 256;
    int sw = (r & 7) << 4;
    #pragma unroll
    for (int i = 0; i < 8; ++i) {
      f32x8 fv = {0.f,0.f,0.f,0.f,0.f,0.f,0.f,0.f};
      if (v) fv = *(const f32x8*)(src + i * 8);
      bf16x8 hv = __builtin_convertvector(fv, bf16x8);
      *(bf16x8*)(dst + (((h * 128 + i * 16) ^ sw))) = hv;
    }
  }
  __syncthreads();

  int l  = t & 63, w = t >> 6;
  int lr = l & 15, lg = l >> 4;

  // ---- A fragments for this wave's 32 rows (2 mfrags x 4 ksteps) ----
  bf16x8 a[2][4];
  #pragma unroll
  for (int mf = 0; mf < 2; ++mf) {
    int r = w * 32 + mf * 16 + lr;
    const char* ap = Fl + r * 256;
    int sw = (r & 7) << 4;
    #pragma unroll
    for (int ks = 0; ks < 4; ++ks)
      a[mf][ks] = *(const bf16x8*)(ap + ((ks * 64 + lg * 16) ^ sw));
  }
  int kA0 = ki[w * 32 + lr];
  int kA1 = ki[w * 32 + 16 + lr];

  f32x4 acc[2][4];
  #pragma unroll
  for (int mf = 0; mf < 2; ++mf)
    #pragma unroll
    for (int f = 0; f < 4; ++f)
      acc[mf][f] = (f32x4){0.f, 0.f, 0.f, 0.f};

  f32x8 zf = {0.f,0.f,0.f,0.f,0.f,0.f,0.f,0.f};
  bf16x8 z8 = __builtin_convertvector(zf, bf16x8);

  // ---- K-vol loop: masked-A MFMA accumulate (rows of other k contribute 0) ----
  #pragma unroll 1
  for (int k = 0; k < KVOL; ++k) {
    const bf16x8* wp = (const bf16x8*)wfrag + (long)k * 16 * 64 + l;
    bf16x8 b[4][4];
    #pragma unroll
    for (int f = 0; f < 4; ++f)
      #pragma unroll
      for (int ks = 0; ks < 4; ++ks)
        b[f][ks] = wp[(f * 4 + ks) * 64];
    bool v0 = (kA0 == k), v1 = (kA1 == k);
    #pragma unroll
    for (int ks = 0; ks < 4; ++ks) {
      bf16x8 a0 = sel8(v0, a[0][ks], z8);
      bf16x8 a1 = sel8(v1, a[1][ks], z8);
      #pragma unroll
      for (int f = 0; f < 4; ++f) {
        acc[0][f] = __builtin_amdgcn_mfma_f32_16x16x32_bf16(a0, b[f][ks], acc[0][f], 0, 0, 0);
        acc[1][f] = __builtin_amdgcn_mfma_f32_16x16x32_bf16(a1, b[f][ks], acc[1][f], 0, 0, 0);
      }
    }
  }

  // ---- store + per-column partial stats ----
  float s[4] = {0.f,0.f,0.f,0.f}, q[4] = {0.f,0.f,0.f,0.f};
  #pragma unroll
  for (int mf = 0; mf < 2; ++mf)
    #pragma unroll
    for (int f = 0; f < 4; ++f)
      #pragma unroll
      for (int reg = 0; reg < 4; ++reg) {
        int row = w * 32 + mf * 16 + lg * 4 + reg;
        int m = m0 + row;
        float vv = acc[mf][f][reg];
        s[f] += vv; q[f] += vv * vv;           // invalid rows are exactly 0
        if (m < M) out[(long)m * COUT + f * 16 + lr] = vv;
      }

  __syncthreads();                              // done with Fl; reuse as scratch
  float* redS = (float*)Fl;                     // [16][64]
  float* redQ = redS + 1024;                    // [16][64]
  int gi = w * 4 + lg;
  #pragma unroll
  for (int f = 0; f < 4; ++f) {
    redS[gi * 64 + f * 16 + lr] = s[f];
    redQ[gi * 64 + f * 16 + lr] = q[f];
  }
  __syncthreads();
  if (t < COUT) {
    float fs = 0.f, fq = 0.f;
    #pragma unroll
    for (int g2 = 0; g2 < 16; ++g2) { fs += redS[g2 * 64 + t]; fq += redQ[g2 * 64 + t]; }
    atomicAdd(&gsum[t], fs);
    atomicAdd(&gsq[t], fq);
  }
}

__global__ void k_norm(float* __restrict__ out,
                       const float* __restrict__ gsum, const float* __restrict__ gsq,
                       const float* __restrict__ gamma, const float* __restrict__ beta,
                       int M) {
  long total = (long)M * COUT / 4;
  long T0 = (long)blockIdx.x * blockDim.x + threadIdx.x;
  int c0 = (int)((T0 * 4) & 63);
  float4 sm = *(const float4*)&gsum[c0];
  float4 sq = *(const float4*)&gsq[c0];
  float inv = 1.0f / (float)M;
  float mx = sm.x * inv, my = sm.y * inv, mz = sm.z * inv, mw = sm.w * inv;
  float rx = rsqrtf(sq.x * inv - mx * mx + BN_EPS);
  float ry = rsqrtf(sq.y * inv - my * my + BN_EPS);
  float rz = rsqrtf(sq.z * inv - mz * mz + BN_EPS);
  float rw = rsqrtf(sq.w * inv - mw * mw + BN_EPS);
  float4 ga = *(const float4*)&gamma[c0];
  float4 be = *(const float4*)&beta[c0];
  float scx = rx * ga.x, scy = ry * ga.y, scz = rz * ga.z, scw = rw * ga.w;
  float shx = be.x - mx * scx, shy = be.y - my * scy;
  float shz = be.z - mz * scz, shw = be.w - mw * scw;
  float4* o4 = (float4*)out;
  long stride = (long)gridDim.x * blockDim.x;
  for (long j = T0; j < total; j += stride) {
    float4 v = o4[j];
    v.x = fmaxf(fmaf(v.x, scx, shx), 0.f);
    v.y = fmaxf(fmaf(v.y, scy, shy), 0.f);
    v.z = fmaxf(fmaf(v.z, scz, shz), 0.f);
    v.w = fmaxf(fmaf(v.w, scw, shw), 0.f);
    o4[j] = v;
  }
}

extern "C" void kernel_launch(void* const* d_in, const int* in_sizes, int n_in,
                              void* d_out, int out_size, void* d_ws, size_t ws_size,
                              hipStream_t stream) {
  const float* feats  = (const float*)d_in[0];
  const float* weight = (const float*)d_in[1];
  const float* gamma  = (const float*)d_in[2];
  const float* beta   = (const float*)d_in[3];
  const int*   in_idx = (const int*)d_in[4];
  const int*   kidx   = (const int*)d_in[5];
  int M = in_sizes[4];
  float* out = (float*)d_out;

  float*  gsum  = (float*)((char*)d_ws + 128);
  float*  gsq   = (float*)((char*)d_ws + 384);
  __bf16* wfrag = (__bf16*)((char*)d_ws + 1024);

  hipMemsetAsync(d_ws, 0, 1024, stream);
  k_prepw<<<128, 256, 0, stream>>>(weight, wfrag);

  int nb = (M + TMR - 1) / TMR;
  k_gemm<<<nb, 256, 0, stream>>>(feats, in_idx, kidx, wfrag, out, gsum, gsq, M);

  k_norm<<<2048, 256, 0, stream>>>(out, gsum, gsq, gamma, beta, M);
}